// Round 7
// baseline (131.398 us; speedup 1.0000x reference)
//
#include <hip/hip_runtime.h>
#include <hip/hip_bf16.h>

// Eq2NetSet via bf16 MFMA (16x16x32, fp32 accum) — R7: barrier-free register-chained MLP.
// Each wave: 32 pairs (N) x 128 channels (M), acc[8][2].  The A-fragment (weight) pack
// for W2/W3 uses the permuted k-map L(kq,q,j)=32kq+16(j>>2)+4q+(j&3) so that the MFMA
// C/D output, relu'd and bf16-packed pairwise, IS the next layer's B-fragment in the
// same lane's registers: no LDS round-trip, no __syncthreads between layers.
// L1 B-fragments come from direct global x-row loads (natural d-order, W1 packed natural).
// Single 2KB LDS exchange at the end combines the block's 4 waves -> partial[b][tile][128].
// Partials -> fused reduce+decode kernel (unchanged from R6).

#define NB 4
#define NN 256
#define HD 128
#define TPB 257    // tiles per batch: 32896 pairs / 128

typedef __attribute__((ext_vector_type(8))) short bf16x8;
typedef __attribute__((ext_vector_type(4))) float f32x4;

// two fp32 -> packed bf16 pair (RNE), lo = a, hi = b
__device__ __forceinline__ unsigned rne2(float a, float b) {
    unsigned ua = __builtin_bit_cast(unsigned, a);
    unsigned ub = __builtin_bit_cast(unsigned, b);
    ua = ua + 0x7fff + ((ua >> 16) & 1);
    ub = ub + 0x7fff + ((ub >> 16) & 1);
    return (ua >> 16) | (ub & 0xffff0000u);
}

__device__ __forceinline__ short f2bf(float f) {
    unsigned u = __builtin_bit_cast(unsigned, f);
    u = (u + 0x7fff + ((u >> 16) & 1)) >> 16;
    return (short)u;
}

__device__ __forceinline__ void tri_ij(int t, int& i, int& j) {
    j = (int)((sqrtf(8.0f * (float)t + 1.0f) - 1.0f) * 0.5f);
    while (((j + 1) * (j + 2) >> 1) <= t) ++j;
    while (((j * (j + 1)) >> 1) > t) --j;
    i = t - ((j * (j + 1)) >> 1);
}

// natural pack (W1): slot (mt,kq,lane,j) <- W[kq*32 + (lane>>4)*8 + j][mt*16 + (lane&15)]
__device__ __forceinline__ void pack_w_nat(const float* __restrict__ W, short* __restrict__ pw,
                                           int KQ, int u) {
    int l  = u & 63;
    int kq = (u >> 6) % KQ;
    int mt = (u >> 6) / KQ;
    int q = l >> 4, m = l & 15;
    int c = mt * 16 + m;
#pragma unroll
    for (int j = 0; j < 8; ++j) {
        int k = kq * 32 + q * 8 + j;
        pw[u * 8 + j] = f2bf(W[k * 128 + c]);
    }
}

// permuted pack (W2/W3): slot (mt,kq,lane,j) <- W[32kq + 16(j>>2) + 4(lane>>4) + (j&3)][mt*16+(lane&15)]
// This makes the previous layer's packed C/D registers directly usable as the B-fragment.
__device__ __forceinline__ void pack_w_perm(const float* __restrict__ W, short* __restrict__ pw,
                                            int u) {
    int l  = u & 63;
    int kq = (u >> 6) & 3;     // KQ = 4
    int mt = (u >> 6) >> 2;
    int q = l >> 4, m = l & 15;
    int c = mt * 16 + m;
#pragma unroll
    for (int j = 0; j < 8; ++j) {
        int k = 32 * kq + 16 * (j >> 2) + 4 * q + (j & 3);
        pw[u * 8 + j] = f2bf(W[k * 128 + c]);
    }
}

__global__ void prep_kernel(const int* __restrict__ xcat,
                            const float* __restrict__ xfeat,
                            const float* __restrict__ emb,
                            const float* __restrict__ W1,
                            const float* __restrict__ W2,
                            const float* __restrict__ W3,
                            float* __restrict__ x,
                            short* __restrict__ pw1,
                            short* __restrict__ pw2,
                            short* __restrict__ pw3)
{
    int bid = blockIdx.x;
    int tid = threadIdx.x;
    if (bid < 256) {                       // build x[4][256][64] fp32
        int f = bid * 256 + tid;
        int d = f & 63;
        int nn = f >> 6;                   // b*256+n
        float v;
        if (d < 63) v = emb[xcat[nn] * 63 + d];
        else        v = xfeat[nn];
        x[f] = v;
    } else if (bid < 260) {                // W1: 8mt*2kq*64 = 1024 threads (natural)
        pack_w_nat(W1, pw1, 2, (bid - 256) * 256 + tid);
    } else if (bid < 268) {                // W2: 8mt*4kq*64 = 2048 (permuted)
        pack_w_perm(W2, pw2, (bid - 260) * 256 + tid);
    } else {                               // W3 (permuted)
        pack_w_perm(W3, pw3, (bid - 268) * 256 + tid);
    }
}

__global__ __launch_bounds__(256, 3) void pair_mlp(
    const float* __restrict__ x,
    const short* __restrict__ pw1, const float* __restrict__ b1,
    const short* __restrict__ pw2, const float* __restrict__ b2,
    const short* __restrict__ pw3, const float* __restrict__ b3,
    float* __restrict__ partialOut)
{
    __shared__ float smPart[4][HD];    // 2 KB — the only LDS

    const int tid = threadIdx.x;
    const int w = __builtin_amdgcn_readfirstlane(tid >> 6);  // wave 0..3
    const int l = tid & 63;
    const int q = l >> 4;
    const int n = l & 15;
    const int b = blockIdx.y;
    const float* xb = x + (b << 14);

    // this wave's two pairs (nt=0,1)
    const int p0 = blockIdx.x * 128 + w * 32 + n;
    int i0, j0, i1, j1;
    tri_ij(p0, i0, j0);
    tri_ij(p0 + 16, i1, j1);
    const float wp0 = (i0 == j0) ? 1.0f : 2.0f;
    const float wp1 = (i1 == j1) ? 1.0f : 2.0f;

    // ---- L1 B-fragments: direct global products, natural d order ----
    bf16x8 bp[2][2];    // [nt][kq]
    {
        const float* xi[2] = {xb + (i0 << 6), xb + (i1 << 6)};
        const float* xj[2] = {xb + (j0 << 6), xb + (j1 << 6)};
#pragma unroll
        for (int nt = 0; nt < 2; ++nt)
#pragma unroll
            for (int kq = 0; kq < 2; ++kq) {
                int dd = kq * 32 + q * 8;
                float4 A0 = *(const float4*)(xi[nt] + dd);
                float4 A1 = *(const float4*)(xi[nt] + dd + 4);
                float4 B0 = *(const float4*)(xj[nt] + dd);
                float4 B1 = *(const float4*)(xj[nt] + dd + 4);
                uint4 s;
                s.x = rne2(A0.x * B0.x, A0.y * B0.y);
                s.y = rne2(A0.z * B0.z, A0.w * B0.w);
                s.z = rne2(A1.x * B1.x, A1.y * B1.y);
                s.w = rne2(A1.z * B1.z, A1.w * B1.w);
                bp[nt][kq] = __builtin_bit_cast(bf16x8, s);
            }
    }

    f32x4 acc[8][2];
    unsigned pk[2][8][2];   // [nt][mt][dword] packed relu'd bf16 pairs

    // ---- L1: K=64, acc init = b1 ----
#pragma unroll
    for (int mt = 0; mt < 8; ++mt) {
        float4 bv = *(const float4*)(b1 + mt * 16 + q * 4);
        f32x4 init = {bv.x, bv.y, bv.z, bv.w};
        acc[mt][0] = init; acc[mt][1] = init;
    }
#pragma unroll
    for (int kq = 0; kq < 2; ++kq)
#pragma unroll
        for (int mt = 0; mt < 8; ++mt) {
            bf16x8 afr = *(const bf16x8*)(pw1 + (((mt * 2 + kq) * 64 + l) << 3));
            acc[mt][0] = __builtin_amdgcn_mfma_f32_16x16x32_bf16(afr, bp[0][kq], acc[mt][0], 0, 0, 0);
            acc[mt][1] = __builtin_amdgcn_mfma_f32_16x16x32_bf16(afr, bp[1][kq], acc[mt][1], 0, 0, 0);
        }

    // relu + pack (C/D -> next B, in registers)
#pragma unroll
    for (int nt = 0; nt < 2; ++nt)
#pragma unroll
        for (int mt = 0; mt < 8; ++mt) {
            pk[nt][mt][0] = rne2(fmaxf(acc[mt][nt][0], 0.f), fmaxf(acc[mt][nt][1], 0.f));
            pk[nt][mt][1] = rne2(fmaxf(acc[mt][nt][2], 0.f), fmaxf(acc[mt][nt][3], 0.f));
        }

    // ---- L2: K=128, acc init = b2 ----
#pragma unroll
    for (int mt = 0; mt < 8; ++mt) {
        float4 bv = *(const float4*)(b2 + mt * 16 + q * 4);
        f32x4 init = {bv.x, bv.y, bv.z, bv.w};
        acc[mt][0] = init; acc[mt][1] = init;
    }
#pragma unroll
    for (int kq = 0; kq < 4; ++kq) {
        uint4 u0 = {pk[0][2 * kq][0], pk[0][2 * kq][1], pk[0][2 * kq + 1][0], pk[0][2 * kq + 1][1]};
        uint4 u1 = {pk[1][2 * kq][0], pk[1][2 * kq][1], pk[1][2 * kq + 1][0], pk[1][2 * kq + 1][1]};
        bf16x8 bf0 = __builtin_bit_cast(bf16x8, u0);
        bf16x8 bf1 = __builtin_bit_cast(bf16x8, u1);
#pragma unroll
        for (int mt = 0; mt < 8; ++mt) {
            bf16x8 afr = *(const bf16x8*)(pw2 + (((mt * 4 + kq) * 64 + l) << 3));
            acc[mt][0] = __builtin_amdgcn_mfma_f32_16x16x32_bf16(afr, bf0, acc[mt][0], 0, 0, 0);
            acc[mt][1] = __builtin_amdgcn_mfma_f32_16x16x32_bf16(afr, bf1, acc[mt][1], 0, 0, 0);
        }
    }

#pragma unroll
    for (int nt = 0; nt < 2; ++nt)
#pragma unroll
        for (int mt = 0; mt < 8; ++mt) {
            pk[nt][mt][0] = rne2(fmaxf(acc[mt][nt][0], 0.f), fmaxf(acc[mt][nt][1], 0.f));
            pk[nt][mt][1] = rne2(fmaxf(acc[mt][nt][2], 0.f), fmaxf(acc[mt][nt][3], 0.f));
        }

    // ---- L3: K=128, acc init = b3 ----
#pragma unroll
    for (int mt = 0; mt < 8; ++mt) {
        float4 bv = *(const float4*)(b3 + mt * 16 + q * 4);
        f32x4 init = {bv.x, bv.y, bv.z, bv.w};
        acc[mt][0] = init; acc[mt][1] = init;
    }
#pragma unroll
    for (int kq = 0; kq < 4; ++kq) {
        uint4 u0 = {pk[0][2 * kq][0], pk[0][2 * kq][1], pk[0][2 * kq + 1][0], pk[0][2 * kq + 1][1]};
        uint4 u1 = {pk[1][2 * kq][0], pk[1][2 * kq][1], pk[1][2 * kq + 1][0], pk[1][2 * kq + 1][1]};
        bf16x8 bf0 = __builtin_bit_cast(bf16x8, u0);
        bf16x8 bf1 = __builtin_bit_cast(bf16x8, u1);
#pragma unroll
        for (int mt = 0; mt < 8; ++mt) {
            bf16x8 afr = *(const bf16x8*)(pw3 + (((mt * 4 + kq) * 64 + l) << 3));
            acc[mt][0] = __builtin_amdgcn_mfma_f32_16x16x32_bf16(afr, bf0, acc[mt][0], 0, 0, 0);
            acc[mt][1] = __builtin_amdgcn_mfma_f32_16x16x32_bf16(afr, bf1, acc[mt][1], 0, 0, 0);
        }
    }

    // ---- reduce over this wave's 32 pairs: relu * pair-weight, butterfly over n ----
#pragma unroll
    for (int mt = 0; mt < 8; ++mt) {
        float vs[4];
#pragma unroll
        for (int r = 0; r < 4; ++r) {
            float v = wp0 * fmaxf(acc[mt][0][r], 0.f) + wp1 * fmaxf(acc[mt][1][r], 0.f);
            v += __shfl_xor(v, 1, 64);
            v += __shfl_xor(v, 2, 64);
            v += __shfl_xor(v, 4, 64);
            v += __shfl_xor(v, 8, 64);
            vs[r] = v;
        }
        if (n == 0) {
            float4 o = {vs[0], vs[1], vs[2], vs[3]};
            *(float4*)(&smPart[w][mt * 16 + q * 4]) = o;
        }
    }
    __syncthreads();

    if (tid < HD) {
        float v = (smPart[0][tid] + smPart[1][tid]) + (smPart[2][tid] + smPart[3][tid]);
        partialOut[(b * TPB + blockIdx.x) * HD + tid] = v;
    }
}

// fused reduce + decoder: one block per batch, 1024 threads.
__global__ __launch_bounds__(1024) void reduce_decode(
    const float* __restrict__ partial,
    const float* __restrict__ D1, const float* __restrict__ c1,
    const float* __restrict__ D2, const float* __restrict__ c2,
    const float* __restrict__ D3, const float* __restrict__ c3,
    float* __restrict__ out)
{
    __shared__ float red8[8][HD];
    __shared__ float red2[2][HD];
    __shared__ float hb[HD];
    __shared__ float tb[HD];
    const int b = blockIdx.x;
    const int t = threadIdx.x;          // 1024 threads
    const int ch = t & 127, sl = t >> 7;   // slice 0..7

    // Phase A: sum tiles tl = sl, sl+8, ... (unrolled x4 for load batching)
    {
        const float* base = partial + b * TPB * HD + ch;
        float s0 = 0.f, s1 = 0.f, s2 = 0.f, s3 = 0.f;
        int tl = sl;
        for (; tl + 32 <= TPB; tl += 32) {
            s0 += base[(tl     ) * HD];
            s1 += base[(tl +  8) * HD];
            s2 += base[(tl + 16) * HD];
            s3 += base[(tl + 24) * HD];
        }
        for (; tl < TPB; tl += 8) s0 += base[tl * HD];
        red8[sl][ch] = (s0 + s1) + (s2 + s3);
    }
    __syncthreads();
    if (sl == 0) {
        float v = ((red8[0][ch] + red8[1][ch]) + (red8[2][ch] + red8[3][ch]))
                + ((red8[4][ch] + red8[5][ch]) + (red8[6][ch] + red8[7][ch]));
        hb[ch] = fmaxf(v * (1.0f / 65536.0f), 0.0f);
    }
    __syncthreads();

    const int hf = sl & 1;

    // dec layer 1 (split-k over 2 halves, 256 threads)
    if (t < 256) {
        float a = 0.f;
        for (int k = hf * 64; k < hf * 64 + 64; ++k)
            a = fmaf(hb[k], D1[(k << 7) + ch], a);
        red2[hf][ch] = a;
    }
    __syncthreads();
    if (t < 128)
        tb[ch] = fmaxf(red2[0][ch] + red2[1][ch] + c1[ch], 0.0f);
    __syncthreads();

    // dec layer 2
    if (t < 256) {
        float a = 0.f;
        for (int k = hf * 64; k < hf * 64 + 64; ++k)
            a = fmaf(tb[k], D2[(k << 7) + ch], a);
        red2[hf][ch] = a;
    }
    __syncthreads();
    if (t < 128)
        hb[ch] = fmaxf(red2[0][ch] + red2[1][ch] + c2[ch], 0.0f);
    __syncthreads();

    // dec layer 3: out[b] = dot(hb, D3) + c3
    if (t < 128) red2[0][ch] = hb[ch] * D3[ch];
    __syncthreads();
    if (t < 64) {
        float r = red2[0][t] + red2[0][t + 64];
#pragma unroll
        for (int s2 = 1; s2 < 64; s2 <<= 1)
            r += __shfl_xor(r, s2, 64);
        if (t == 0) out[b] = r + c3[0];
    }
}

extern "C" void kernel_launch(void* const* d_in, const int* in_sizes, int n_in,
                              void* d_out, int out_size, void* d_ws, size_t ws_size,
                              hipStream_t stream)
{
    (void)in_sizes; (void)n_in; (void)out_size; (void)ws_size;

    const int*   xcat  = (const int*)  d_in[0];
    const float* xfeat = (const float*)d_in[1];
    const float* emb   = (const float*)d_in[2];
    const float* W1    = (const float*)d_in[3];
    const float* b1    = (const float*)d_in[4];
    const float* W2    = (const float*)d_in[5];
    const float* b2    = (const float*)d_in[6];
    const float* W3    = (const float*)d_in[7];
    const float* b3    = (const float*)d_in[8];
    const float* D1    = (const float*)d_in[9];
    const float* c1    = (const float*)d_in[10];
    const float* D2    = (const float*)d_in[11];
    const float* c2    = (const float*)d_in[12];
    const float* D3    = (const float*)d_in[13];
    const float* c3    = (const float*)d_in[14];
    float* out = (float*)d_out;

    float* x       = (float*)d_ws;                    // 65536 f
    short* pw1     = (short*)(x + NB * NN * 64);      // 8192 s
    short* pw2     = pw1 + 8 * 2 * 64 * 8;            // 16384 s
    short* pw3     = pw2 + 8 * 4 * 64 * 8;            // 16384 s
    float* partial = (float*)(pw3 + 8 * 4 * 64 * 8);  // 4*257*128 f

    prep_kernel<<<276, 256, 0, stream>>>(xcat, xfeat, emb, W1, W2, W3,
                                         x, pw1, pw2, pw3);
    pair_mlp<<<dim3(TPB, NB), 256, 0, stream>>>(x, pw1, b1, pw2, b2, pw3, b3, partial);
    reduce_decode<<<NB, 1024, 0, stream>>>(partial, D1, c1, D2, c2, D3, c3, out);
}

// Round 8
// 131.021 us; speedup vs baseline: 1.0029x; 1.0029x over previous
//
#include <hip/hip_runtime.h>
#include <hip/hip_bf16.h>

// Eq2NetSet via bf16 MFMA (16x16x32, fp32 accum) — R8: LDS-staged weights + 64 pairs/wave.
// R7 post-mortem: bottleneck = per-wave weight-fragment loads from L2 (329 MB redundant,
// latency-exposed). Fix: 512-thread blocks stage all 80 KB packed weights into 64 KB LDS
// (H0/H1 overlay: pw1->H0[0:16K), pw2->H1, pw3 held in 16 VGPRs then written over H0
// after L1), waves read frags via ds_read_b128.  nt=4 (64 pairs/wave) halves weight
// traffic per pair: 80 frag reads feed 320 MFMA.  R7's permuted W2/W3 pack keeps the
// layer->layer transform in registers (no activation LDS, no mid-layer barriers).
//   L(kq,q,j) = 32kq + 16(j>>2) + 4q + (j&3)  maps C/D regs directly to next B-frag.

#define NB 4
#define NN 256
#define HD 128
#define BPB 65     // blocks per batch: ceil(32896 / 512)
#define NPAIR 32896

typedef __attribute__((ext_vector_type(8))) short bf16x8;
typedef __attribute__((ext_vector_type(4))) float f32x4;

__device__ __forceinline__ unsigned rne2(float a, float b) {
    unsigned ua = __builtin_bit_cast(unsigned, a);
    unsigned ub = __builtin_bit_cast(unsigned, b);
    ua = ua + 0x7fff + ((ua >> 16) & 1);
    ub = ub + 0x7fff + ((ub >> 16) & 1);
    return (ua >> 16) | (ub & 0xffff0000u);
}

__device__ __forceinline__ short f2bf(float f) {
    unsigned u = __builtin_bit_cast(unsigned, f);
    u = (u + 0x7fff + ((u >> 16) & 1)) >> 16;
    return (short)u;
}

__device__ __forceinline__ void tri_ij(int t, int& i, int& j) {
    j = (int)((sqrtf(8.0f * (float)t + 1.0f) - 1.0f) * 0.5f);
    while (((j + 1) * (j + 2) >> 1) <= t) ++j;
    while (((j * (j + 1)) >> 1) > t) --j;
    i = t - ((j * (j + 1)) >> 1);
}

// natural pack (W1): slot (mt,kq,lane,j) <- W[kq*32 + (lane>>4)*8 + j][mt*16 + (lane&15)]
__device__ __forceinline__ void pack_w_nat(const float* __restrict__ W, short* __restrict__ pw,
                                           int KQ, int u) {
    int l  = u & 63;
    int kq = (u >> 6) % KQ;
    int mt = (u >> 6) / KQ;
    int q = l >> 4, m = l & 15;
    int c = mt * 16 + m;
#pragma unroll
    for (int j = 0; j < 8; ++j) {
        int k = kq * 32 + q * 8 + j;
        pw[u * 8 + j] = f2bf(W[k * 128 + c]);
    }
}

// permuted pack (W2/W3): slot (mt,kq,lane,j) <- W[32kq+16(j>>2)+4(lane>>4)+(j&3)][mt*16+(lane&15)]
__device__ __forceinline__ void pack_w_perm(const float* __restrict__ W, short* __restrict__ pw,
                                            int u) {
    int l  = u & 63;
    int kq = (u >> 6) & 3;
    int mt = (u >> 6) >> 2;
    int q = l >> 4, m = l & 15;
    int c = mt * 16 + m;
#pragma unroll
    for (int j = 0; j < 8; ++j) {
        int k = 32 * kq + 16 * (j >> 2) + 4 * q + (j & 3);
        pw[u * 8 + j] = f2bf(W[k * 128 + c]);
    }
}

__global__ void prep_kernel(const int* __restrict__ xcat,
                            const float* __restrict__ xfeat,
                            const float* __restrict__ emb,
                            const float* __restrict__ W1,
                            const float* __restrict__ W2,
                            const float* __restrict__ W3,
                            float* __restrict__ x,
                            short* __restrict__ pw1,
                            short* __restrict__ pw2,
                            short* __restrict__ pw3)
{
    int bid = blockIdx.x;
    int tid = threadIdx.x;
    if (bid < 256) {                       // build x[4][256][64] fp32
        int f = bid * 256 + tid;
        int d = f & 63;
        int nn = f >> 6;
        float v;
        if (d < 63) v = emb[xcat[nn] * 63 + d];
        else        v = xfeat[nn];
        x[f] = v;
    } else if (bid < 260) {
        pack_w_nat(W1, pw1, 2, (bid - 256) * 256 + tid);
    } else if (bid < 268) {
        pack_w_perm(W2, pw2, (bid - 260) * 256 + tid);
    } else {
        pack_w_perm(W3, pw3, (bid - 268) * 256 + tid);
    }
}

__global__ __launch_bounds__(512, 2) void pair_mlp(
    const float* __restrict__ x,
    const short* __restrict__ pw1g, const float* __restrict__ b1,
    const short* __restrict__ pw2g, const float* __restrict__ b2,
    const short* __restrict__ pw3g, const float* __restrict__ b3,
    float* __restrict__ partialOut)
{
    __shared__ __align__(16) short smW[32768];   // 64 KB: H0 = [0,32KB), H1 = [32KB,64KB)

    const int tid = threadIdx.x;
    const int w = __builtin_amdgcn_readfirstlane(tid >> 6);  // wave 0..7
    const int l = tid & 63;
    const int q = l >> 4;
    const int n = l & 15;
    const int b = blockIdx.y;
    const float* xb = x + (b << 14);

    // ---- stage weights: pw1->H0[0:16K), pw2->H1; pw3 preloaded to regs ----
    float4* H0w = (float4*)smW;                    // 2048 float4 (32 KB)
    float4* H1w = (float4*)(smW + 16384);          // byte offset 32768
    const float4* s1 = (const float4*)pw1g;        // 1024 float4
    const float4* s2 = (const float4*)pw2g;        // 2048 float4
    const float4* s3 = (const float4*)pw3g;        // 2048 float4
    float4 g3[4];
    {
        float4 g1a = s1[tid], g1b = s1[tid + 512];
        float4 g2[4];
#pragma unroll
        for (int k = 0; k < 4; ++k) g2[k] = s2[tid + 512 * k];
#pragma unroll
        for (int k = 0; k < 4; ++k) g3[k] = s3[tid + 512 * k];
        H0w[tid] = g1a; H0w[tid + 512] = g1b;
#pragma unroll
        for (int k = 0; k < 4; ++k) H1w[tid + 512 * k] = g2[k];
    }

    // ---- this wave's 64 pairs: nt*16 + n ----
    const int base = blockIdx.x * 512 + w * 64 + n;
    int iv[4], jv[4];
    float wp[4];
#pragma unroll
    for (int nt = 0; nt < 4; ++nt) {
        int praw = base + nt * 16;
        int pc = praw <= (NPAIR - 1) ? praw : (NPAIR - 1);
        tri_ij(pc, iv[nt], jv[nt]);
        wp[nt] = (praw <= (NPAIR - 1)) ? ((iv[nt] == jv[nt]) ? 1.0f : 2.0f) : 0.0f;
    }

    // ---- L1 B-fragments: direct global products, natural d order ----
    bf16x8 bp[4][2];
#pragma unroll
    for (int nt = 0; nt < 4; ++nt) {
        const float* xi = xb + (iv[nt] << 6);
        const float* xj = xb + (jv[nt] << 6);
#pragma unroll
        for (int kq = 0; kq < 2; ++kq) {
            int dd = kq * 32 + q * 8;
            float4 A0 = *(const float4*)(xi + dd);
            float4 A1 = *(const float4*)(xi + dd + 4);
            float4 B0 = *(const float4*)(xj + dd);
            float4 B1 = *(const float4*)(xj + dd + 4);
            uint4 s;
            s.x = rne2(A0.x * B0.x, A0.y * B0.y);
            s.y = rne2(A0.z * B0.z, A0.w * B0.w);
            s.z = rne2(A1.x * B1.x, A1.y * B1.y);
            s.w = rne2(A1.z * B1.z, A1.w * B1.w);
            bp[nt][kq] = __builtin_bit_cast(bf16x8, s);
        }
    }
    __syncthreads();   // barrier 1: pw1/pw2 staged

    const bf16x8* F0 = (const bf16x8*)smW;             // frag idx*64 + l
    const bf16x8* F1 = (const bf16x8*)(smW + 16384);

    f32x4 acc[8][4];
    unsigned pk[4][8][2];

    // ---- L1: K=64, acc init = b1, A-frags from H0 (LDS) ----
#pragma unroll
    for (int mt = 0; mt < 8; ++mt) {
        float4 bv = *(const float4*)(b1 + mt * 16 + q * 4);
        f32x4 init = {bv.x, bv.y, bv.z, bv.w};
#pragma unroll
        for (int nt = 0; nt < 4; ++nt) acc[mt][nt] = init;
    }
#pragma unroll
    for (int kq = 0; kq < 2; ++kq)
#pragma unroll
        for (int mt = 0; mt < 8; ++mt) {
            bf16x8 afr = F0[(mt * 2 + kq) * 64 + l];
#pragma unroll
            for (int nt = 0; nt < 4; ++nt)
                acc[mt][nt] = __builtin_amdgcn_mfma_f32_16x16x32_bf16(afr, bp[nt][kq], acc[mt][nt], 0, 0, 0);
        }

    // relu + pack (C/D -> next B, in registers)
#pragma unroll
    for (int nt = 0; nt < 4; ++nt)
#pragma unroll
        for (int mt = 0; mt < 8; ++mt) {
            pk[nt][mt][0] = rne2(fmaxf(acc[mt][nt][0], 0.f), fmaxf(acc[mt][nt][1], 0.f));
            pk[nt][mt][1] = rne2(fmaxf(acc[mt][nt][2], 0.f), fmaxf(acc[mt][nt][3], 0.f));
        }

    __syncthreads();   // barrier 2: all waves done reading H0 (L1)
    // stage pw3 -> H0 (regs were loaded long ago; pure ds_write)
    H0w[tid] = g3[0]; H0w[tid + 512] = g3[1];
    H0w[tid + 1024] = g3[2]; H0w[tid + 1536] = g3[3];

    // ---- L2: K=128, acc init = b2, A-frags from H1 ----
#pragma unroll
    for (int mt = 0; mt < 8; ++mt) {
        float4 bv = *(const float4*)(b2 + mt * 16 + q * 4);
        f32x4 init = {bv.x, bv.y, bv.z, bv.w};
#pragma unroll
        for (int nt = 0; nt < 4; ++nt) acc[mt][nt] = init;
    }
#pragma unroll
    for (int kq = 0; kq < 4; ++kq) {
        bf16x8 bf[4];
#pragma unroll
        for (int nt = 0; nt < 4; ++nt) {
            uint4 u = {pk[nt][2 * kq][0], pk[nt][2 * kq][1],
                       pk[nt][2 * kq + 1][0], pk[nt][2 * kq + 1][1]};
            bf[nt] = __builtin_bit_cast(bf16x8, u);
        }
#pragma unroll
        for (int mt = 0; mt < 8; ++mt) {
            bf16x8 afr = F1[(mt * 4 + kq) * 64 + l];
#pragma unroll
            for (int nt = 0; nt < 4; ++nt)
                acc[mt][nt] = __builtin_amdgcn_mfma_f32_16x16x32_bf16(afr, bf[nt], acc[mt][nt], 0, 0, 0);
        }
    }

#pragma unroll
    for (int nt = 0; nt < 4; ++nt)
#pragma unroll
        for (int mt = 0; mt < 8; ++mt) {
            pk[nt][mt][0] = rne2(fmaxf(acc[mt][nt][0], 0.f), fmaxf(acc[mt][nt][1], 0.f));
            pk[nt][mt][1] = rne2(fmaxf(acc[mt][nt][2], 0.f), fmaxf(acc[mt][nt][3], 0.f));
        }

    __syncthreads();   // barrier 3: pw3 staged in H0

    // ---- L3: K=128, acc init = b3, A-frags from H0 (pw3) ----
#pragma unroll
    for (int mt = 0; mt < 8; ++mt) {
        float4 bv = *(const float4*)(b3 + mt * 16 + q * 4);
        f32x4 init = {bv.x, bv.y, bv.z, bv.w};
#pragma unroll
        for (int nt = 0; nt < 4; ++nt) acc[mt][nt] = init;
    }
#pragma unroll
    for (int kq = 0; kq < 4; ++kq) {
        bf16x8 bf[4];
#pragma unroll
        for (int nt = 0; nt < 4; ++nt) {
            uint4 u = {pk[nt][2 * kq][0], pk[nt][2 * kq][1],
                       pk[nt][2 * kq + 1][0], pk[nt][2 * kq + 1][1]};
            bf[nt] = __builtin_bit_cast(bf16x8, u);
        }
#pragma unroll
        for (int mt = 0; mt < 8; ++mt) {
            bf16x8 afr = F0[(mt * 4 + kq) * 64 + l];
#pragma unroll
            for (int nt = 0; nt < 4; ++nt)
                acc[mt][nt] = __builtin_amdgcn_mfma_f32_16x16x32_bf16(afr, bf[nt], acc[mt][nt], 0, 0, 0);
        }
    }

    // ---- reduce over this wave's 64 pairs: relu * pair-weight, butterfly over n ----
    const int row = (b * BPB + blockIdx.x) * 8 + w;
#pragma unroll
    for (int mt = 0; mt < 8; ++mt) {
        float vs[4];
#pragma unroll
        for (int r = 0; r < 4; ++r) {
            float v = wp[0] * fmaxf(acc[mt][0][r], 0.f) + wp[1] * fmaxf(acc[mt][1][r], 0.f)
                    + wp[2] * fmaxf(acc[mt][2][r], 0.f) + wp[3] * fmaxf(acc[mt][3][r], 0.f);
            v += __shfl_xor(v, 1, 64);
            v += __shfl_xor(v, 2, 64);
            v += __shfl_xor(v, 4, 64);
            v += __shfl_xor(v, 8, 64);
            vs[r] = v;
        }
        if (n == 0) {
            float4 o = {vs[0], vs[1], vs[2], vs[3]};
            *(float4*)(partialOut + row * HD + mt * 16 + q * 4) = o;
        }
    }
}

// fused reduce + decoder: one block per batch, 1024 threads; R = 520 rows/batch.
#define RROWS (BPB * 8)
__global__ __launch_bounds__(1024) void reduce_decode(
    const float* __restrict__ partial,
    const float* __restrict__ D1, const float* __restrict__ c1,
    const float* __restrict__ D2, const float* __restrict__ c2,
    const float* __restrict__ D3, const float* __restrict__ c3,
    float* __restrict__ out)
{
    __shared__ float red8[8][HD];
    __shared__ float red2[2][HD];
    __shared__ float hb[HD];
    __shared__ float tb[HD];
    const int b = blockIdx.x;
    const int t = threadIdx.x;
    const int ch = t & 127, sl = t >> 7;

    {
        const float* base = partial + b * RROWS * HD + ch;
        float s0 = 0.f, s1 = 0.f, s2 = 0.f, s3 = 0.f;
        int tl = sl;
        for (; tl + 32 <= RROWS; tl += 32) {
            s0 += base[(tl     ) * HD];
            s1 += base[(tl +  8) * HD];
            s2 += base[(tl + 16) * HD];
            s3 += base[(tl + 24) * HD];
        }
        for (; tl < RROWS; tl += 8) s0 += base[tl * HD];
        red8[sl][ch] = (s0 + s1) + (s2 + s3);
    }
    __syncthreads();
    if (sl == 0) {
        float v = ((red8[0][ch] + red8[1][ch]) + (red8[2][ch] + red8[3][ch]))
                + ((red8[4][ch] + red8[5][ch]) + (red8[6][ch] + red8[7][ch]));
        hb[ch] = fmaxf(v * (1.0f / 65536.0f), 0.0f);
    }
    __syncthreads();

    const int hf = sl & 1;

    if (t < 256) {
        float a = 0.f;
        for (int k = hf * 64; k < hf * 64 + 64; ++k)
            a = fmaf(hb[k], D1[(k << 7) + ch], a);
        red2[hf][ch] = a;
    }
    __syncthreads();
    if (t < 128)
        tb[ch] = fmaxf(red2[0][ch] + red2[1][ch] + c1[ch], 0.0f);
    __syncthreads();

    if (t < 256) {
        float a = 0.f;
        for (int k = hf * 64; k < hf * 64 + 64; ++k)
            a = fmaf(tb[k], D2[(k << 7) + ch], a);
        red2[hf][ch] = a;
    }
    __syncthreads();
    if (t < 128)
        hb[ch] = fmaxf(red2[0][ch] + red2[1][ch] + c2[ch], 0.0f);
    __syncthreads();

    if (t < 128) red2[0][ch] = hb[ch] * D3[ch];
    __syncthreads();
    if (t < 64) {
        float r = red2[0][t] + red2[0][t + 64];
#pragma unroll
        for (int s2 = 1; s2 < 64; s2 <<= 1)
            r += __shfl_xor(r, s2, 64);
        if (t == 0) out[b] = r + c3[0];
    }
}

extern "C" void kernel_launch(void* const* d_in, const int* in_sizes, int n_in,
                              void* d_out, int out_size, void* d_ws, size_t ws_size,
                              hipStream_t stream)
{
    (void)in_sizes; (void)n_in; (void)out_size; (void)ws_size;

    const int*   xcat  = (const int*)  d_in[0];
    const float* xfeat = (const float*)d_in[1];
    const float* emb   = (const float*)d_in[2];
    const float* W1    = (const float*)d_in[3];
    const float* b1    = (const float*)d_in[4];
    const float* W2    = (const float*)d_in[5];
    const float* b2    = (const float*)d_in[6];
    const float* W3    = (const float*)d_in[7];
    const float* b3    = (const float*)d_in[8];
    const float* D1    = (const float*)d_in[9];
    const float* c1    = (const float*)d_in[10];
    const float* D2    = (const float*)d_in[11];
    const float* c2    = (const float*)d_in[12];
    const float* D3    = (const float*)d_in[13];
    const float* c3    = (const float*)d_in[14];
    float* out = (float*)d_out;

    float* x       = (float*)d_ws;                    // 65536 f
    short* pw1     = (short*)(x + NB * NN * 64);      // 8192 s  (16 KB)
    short* pw2     = pw1 + 8 * 2 * 64 * 8;            // 16384 s (32 KB)
    short* pw3     = pw2 + 8 * 4 * 64 * 8;            // 16384 s (32 KB)
    float* partial = (float*)(pw3 + 8 * 4 * 64 * 8);  // 4*65*8*128 f

    prep_kernel<<<276, 256, 0, stream>>>(xcat, xfeat, emb, W1, W2, W3,
                                         x, pw1, pw2, pw3);
    pair_mlp<<<dim3(BPB, NB), 512, 0, stream>>>(x, pw1, b1, pw2, b2, pw3, b3, partial);
    reduce_decode<<<NB, 1024, 0, stream>>>(partial, D1, c1, D2, c2, D3, c3, out);
}

// Round 9
// 128.950 us; speedup vs baseline: 1.0190x; 1.0161x over previous
//
#include <hip/hip_runtime.h>
#include <hip/hip_bf16.h>

// Eq2NetSet via bf16 MFMA (16x16x32, fp32 accum) — R9: R8's LDS weight staging, spill-free.
// R8 failed on register spills (acc[8][4] ~280 VGPR > pool; FETCH/WRITE showed 17 MB scratch).
// R9: nt=2 (32 pairs/wave), acc[8][2] -> ~160 VGPR, 512-thread blocks fit 8 waves/CU.
// Structure: stage pw1+pw2 into 64 KB LDS (H0/H1), pw3 rides in 16 VGPRs and overwrites
// H0 after L1.  Permuted W2/W3 pack keeps layer->layer transform in registers
// (L(kq,q,j)=32kq+16(j>>2)+4q+(j&3)).  x-gather issued between staging loads and LDS
// writes to overlap both latency chains.  Cross-wave combine reuses dead H1 after L3.

#define NB 4
#define NN 256
#define HD 128
#define BPB 129    // blocks per batch: ceil(32896 / 256)
#define NPAIR 32896

typedef __attribute__((ext_vector_type(8))) short bf16x8;
typedef __attribute__((ext_vector_type(4))) float f32x4;

__device__ __forceinline__ unsigned rne2(float a, float b) {
    unsigned ua = __builtin_bit_cast(unsigned, a);
    unsigned ub = __builtin_bit_cast(unsigned, b);
    ua = ua + 0x7fff + ((ua >> 16) & 1);
    ub = ub + 0x7fff + ((ub >> 16) & 1);
    return (ua >> 16) | (ub & 0xffff0000u);
}

__device__ __forceinline__ short f2bf(float f) {
    unsigned u = __builtin_bit_cast(unsigned, f);
    u = (u + 0x7fff + ((u >> 16) & 1)) >> 16;
    return (short)u;
}

__device__ __forceinline__ void tri_ij(int t, int& i, int& j) {
    j = (int)((sqrtf(8.0f * (float)t + 1.0f) - 1.0f) * 0.5f);
    while (((j + 1) * (j + 2) >> 1) <= t) ++j;
    while (((j * (j + 1)) >> 1) > t) --j;
    i = t - ((j * (j + 1)) >> 1);
}

// natural pack (W1): slot (mt,kq,lane,j) <- W[kq*32 + (lane>>4)*8 + j][mt*16 + (lane&15)]
__device__ __forceinline__ void pack_w_nat(const float* __restrict__ W, short* __restrict__ pw,
                                           int KQ, int u) {
    int l  = u & 63;
    int kq = (u >> 6) % KQ;
    int mt = (u >> 6) / KQ;
    int q = l >> 4, m = l & 15;
    int c = mt * 16 + m;
#pragma unroll
    for (int j = 0; j < 8; ++j) {
        int k = kq * 32 + q * 8 + j;
        pw[u * 8 + j] = f2bf(W[k * 128 + c]);
    }
}

// permuted pack (W2/W3): slot (mt,kq,lane,j) <- W[32kq+16(j>>2)+4(lane>>4)+(j&3)][mt*16+(lane&15)]
__device__ __forceinline__ void pack_w_perm(const float* __restrict__ W, short* __restrict__ pw,
                                            int u) {
    int l  = u & 63;
    int kq = (u >> 6) & 3;
    int mt = (u >> 6) >> 2;
    int q = l >> 4, m = l & 15;
    int c = mt * 16 + m;
#pragma unroll
    for (int j = 0; j < 8; ++j) {
        int k = 32 * kq + 16 * (j >> 2) + 4 * q + (j & 3);
        pw[u * 8 + j] = f2bf(W[k * 128 + c]);
    }
}

__global__ void prep_kernel(const int* __restrict__ xcat,
                            const float* __restrict__ xfeat,
                            const float* __restrict__ emb,
                            const float* __restrict__ W1,
                            const float* __restrict__ W2,
                            const float* __restrict__ W3,
                            float* __restrict__ x,
                            short* __restrict__ pw1,
                            short* __restrict__ pw2,
                            short* __restrict__ pw3)
{
    int bid = blockIdx.x;
    int tid = threadIdx.x;
    if (bid < 256) {                       // build x[4][256][64] fp32
        int f = bid * 256 + tid;
        int d = f & 63;
        int nn = f >> 6;
        float v;
        if (d < 63) v = emb[xcat[nn] * 63 + d];
        else        v = xfeat[nn];
        x[f] = v;
    } else if (bid < 260) {
        pack_w_nat(W1, pw1, 2, (bid - 256) * 256 + tid);
    } else if (bid < 268) {
        pack_w_perm(W2, pw2, (bid - 260) * 256 + tid);
    } else {
        pack_w_perm(W3, pw3, (bid - 268) * 256 + tid);
    }
}

__global__ __launch_bounds__(512, 1) void pair_mlp(
    const float* __restrict__ x,
    const short* __restrict__ pw1g, const float* __restrict__ b1,
    const short* __restrict__ pw2g, const float* __restrict__ b2,
    const short* __restrict__ pw3g, const float* __restrict__ b3,
    float* __restrict__ partialOut)
{
    __shared__ __align__(16) short smW[32768];   // 64 KB: H0 = [0,32KB), H1 = [32KB,64KB)

    const int tid = threadIdx.x;
    const int w = __builtin_amdgcn_readfirstlane(tid >> 6);  // wave 0..7
    const int l = tid & 63;
    const int q = l >> 4;
    const int n = l & 15;
    const int b = blockIdx.y;
    const float* xb = x + (b << 14);

    float4* H0w = (float4*)smW;                    // 2048 float4 (32 KB)
    float4* H1w = (float4*)(smW + 16384);          // byte offset 32768
    const float4* s1 = (const float4*)pw1g;        // 1024 float4
    const float4* s2 = (const float4*)pw2g;        // 2048 float4
    const float4* s3 = (const float4*)pw3g;        // 2048 float4

    // ---- issue staging loads first (latency overlapped with x-gather below) ----
    float4 g1a = s1[tid], g1b = s1[tid + 512];
    float4 g2[4], g3[4];
#pragma unroll
    for (int k = 0; k < 4; ++k) g2[k] = s2[tid + 512 * k];
#pragma unroll
    for (int k = 0; k < 4; ++k) g3[k] = s3[tid + 512 * k];

    // ---- this wave's 32 pairs: nt*16 + n ----
    const int base = blockIdx.x * 256 + w * 32 + n;
    int iv[2], jv[2];
    float wp[2];
#pragma unroll
    for (int nt = 0; nt < 2; ++nt) {
        int praw = base + nt * 16;
        int pc = praw <= (NPAIR - 1) ? praw : (NPAIR - 1);
        tri_ij(pc, iv[nt], jv[nt]);
        wp[nt] = (praw <= (NPAIR - 1)) ? ((iv[nt] == jv[nt]) ? 1.0f : 2.0f) : 0.0f;
    }

    // ---- L1 B-fragments: direct global products, natural d order ----
    bf16x8 bp[2][2];
#pragma unroll
    for (int nt = 0; nt < 2; ++nt) {
        const float* xi = xb + (iv[nt] << 6);
        const float* xj = xb + (jv[nt] << 6);
#pragma unroll
        for (int kq = 0; kq < 2; ++kq) {
            int dd = kq * 32 + q * 8;
            float4 A0 = *(const float4*)(xi + dd);
            float4 A1 = *(const float4*)(xi + dd + 4);
            float4 B0 = *(const float4*)(xj + dd);
            float4 B1 = *(const float4*)(xj + dd + 4);
            uint4 s;
            s.x = rne2(A0.x * B0.x, A0.y * B0.y);
            s.y = rne2(A0.z * B0.z, A0.w * B0.w);
            s.z = rne2(A1.x * B1.x, A1.y * B1.y);
            s.w = rne2(A1.z * B1.z, A1.w * B1.w);
            bp[nt][kq] = __builtin_bit_cast(bf16x8, s);
        }
    }

    // ---- LDS writes (wait on staging loads), then barrier 1 ----
    H0w[tid] = g1a; H0w[tid + 512] = g1b;
#pragma unroll
    for (int k = 0; k < 4; ++k) H1w[tid + 512 * k] = g2[k];
    __syncthreads();   // barrier 1: pw1/pw2 staged

    const bf16x8* F0 = (const bf16x8*)smW;             // frag idx*64 + l
    const bf16x8* F1 = (const bf16x8*)(smW + 16384);

    f32x4 acc[8][2];
    unsigned pk[2][8][2];

    // ---- L1: K=64, acc init = b1, A-frags from H0 (LDS) ----
#pragma unroll
    for (int mt = 0; mt < 8; ++mt) {
        float4 bv = *(const float4*)(b1 + mt * 16 + q * 4);
        f32x4 init = {bv.x, bv.y, bv.z, bv.w};
        acc[mt][0] = init; acc[mt][1] = init;
    }
#pragma unroll
    for (int kq = 0; kq < 2; ++kq)
#pragma unroll
        for (int mt = 0; mt < 8; ++mt) {
            bf16x8 afr = F0[(mt * 2 + kq) * 64 + l];
            acc[mt][0] = __builtin_amdgcn_mfma_f32_16x16x32_bf16(afr, bp[0][kq], acc[mt][0], 0, 0, 0);
            acc[mt][1] = __builtin_amdgcn_mfma_f32_16x16x32_bf16(afr, bp[1][kq], acc[mt][1], 0, 0, 0);
        }

    // relu + pack (C/D -> next B, in registers)
#pragma unroll
    for (int nt = 0; nt < 2; ++nt)
#pragma unroll
        for (int mt = 0; mt < 8; ++mt) {
            pk[nt][mt][0] = rne2(fmaxf(acc[mt][nt][0], 0.f), fmaxf(acc[mt][nt][1], 0.f));
            pk[nt][mt][1] = rne2(fmaxf(acc[mt][nt][2], 0.f), fmaxf(acc[mt][nt][3], 0.f));
        }

    __syncthreads();   // barrier 2: all waves done reading H0 (L1)
    // stage pw3 -> H0 (pure ds_write; overlaps with L2 compute below)
    H0w[tid] = g3[0]; H0w[tid + 512] = g3[1];
    H0w[tid + 1024] = g3[2]; H0w[tid + 1536] = g3[3];

    // ---- L2: K=128, acc init = b2, A-frags from H1 ----
#pragma unroll
    for (int mt = 0; mt < 8; ++mt) {
        float4 bv = *(const float4*)(b2 + mt * 16 + q * 4);
        f32x4 init = {bv.x, bv.y, bv.z, bv.w};
        acc[mt][0] = init; acc[mt][1] = init;
    }
#pragma unroll
    for (int kq = 0; kq < 4; ++kq) {
        bf16x8 bf[2];
#pragma unroll
        for (int nt = 0; nt < 2; ++nt) {
            uint4 u = {pk[nt][2 * kq][0], pk[nt][2 * kq][1],
                       pk[nt][2 * kq + 1][0], pk[nt][2 * kq + 1][1]};
            bf[nt] = __builtin_bit_cast(bf16x8, u);
        }
#pragma unroll
        for (int mt = 0; mt < 8; ++mt) {
            bf16x8 afr = F1[(mt * 4 + kq) * 64 + l];
            acc[mt][0] = __builtin_amdgcn_mfma_f32_16x16x32_bf16(afr, bf[0], acc[mt][0], 0, 0, 0);
            acc[mt][1] = __builtin_amdgcn_mfma_f32_16x16x32_bf16(afr, bf[1], acc[mt][1], 0, 0, 0);
        }
    }

#pragma unroll
    for (int nt = 0; nt < 2; ++nt)
#pragma unroll
        for (int mt = 0; mt < 8; ++mt) {
            pk[nt][mt][0] = rne2(fmaxf(acc[mt][nt][0], 0.f), fmaxf(acc[mt][nt][1], 0.f));
            pk[nt][mt][1] = rne2(fmaxf(acc[mt][nt][2], 0.f), fmaxf(acc[mt][nt][3], 0.f));
        }

    __syncthreads();   // barrier 3: pw3 staged in H0; H1 dead from here

    // ---- L3: K=128, acc init = b3, A-frags from H0 (pw3) ----
#pragma unroll
    for (int mt = 0; mt < 8; ++mt) {
        float4 bv = *(const float4*)(b3 + mt * 16 + q * 4);
        f32x4 init = {bv.x, bv.y, bv.z, bv.w};
        acc[mt][0] = init; acc[mt][1] = init;
    }
#pragma unroll
    for (int kq = 0; kq < 4; ++kq) {
        bf16x8 bf[2];
#pragma unroll
        for (int nt = 0; nt < 2; ++nt) {
            uint4 u = {pk[nt][2 * kq][0], pk[nt][2 * kq][1],
                       pk[nt][2 * kq + 1][0], pk[nt][2 * kq + 1][1]};
            bf[nt] = __builtin_bit_cast(bf16x8, u);
        }
#pragma unroll
        for (int mt = 0; mt < 8; ++mt) {
            bf16x8 afr = F0[(mt * 4 + kq) * 64 + l];
            acc[mt][0] = __builtin_amdgcn_mfma_f32_16x16x32_bf16(afr, bf[0], acc[mt][0], 0, 0, 0);
            acc[mt][1] = __builtin_amdgcn_mfma_f32_16x16x32_bf16(afr, bf[1], acc[mt][1], 0, 0, 0);
        }
    }

    // ---- reduce: relu * pair-weight, butterfly over n, cross-wave via dead H1 ----
    float* smPart = (float*)(smW + 16384);   // 8 waves x 128 floats = 4 KB (H1 dead)
#pragma unroll
    for (int mt = 0; mt < 8; ++mt) {
        float vs[4];
#pragma unroll
        for (int r = 0; r < 4; ++r) {
            float v = wp[0] * fmaxf(acc[mt][0][r], 0.f) + wp[1] * fmaxf(acc[mt][1][r], 0.f);
            v += __shfl_xor(v, 1, 64);
            v += __shfl_xor(v, 2, 64);
            v += __shfl_xor(v, 4, 64);
            v += __shfl_xor(v, 8, 64);
            vs[r] = v;
        }
        if (n == 0) {
            float4 o = {vs[0], vs[1], vs[2], vs[3]};
            *(float4*)(smPart + w * HD + mt * 16 + q * 4) = o;
        }
    }
    __syncthreads();   // barrier 4

    if (tid < HD) {
        float v = 0.f;
#pragma unroll
        for (int ww = 0; ww < 8; ++ww) v += smPart[ww * HD + tid];
        partialOut[(b * BPB + blockIdx.x) * HD + tid] = v;
    }
}

// fused reduce + decoder: one block per batch, 1024 threads; BPB rows/batch.
__global__ __launch_bounds__(1024) void reduce_decode(
    const float* __restrict__ partial,
    const float* __restrict__ D1, const float* __restrict__ c1,
    const float* __restrict__ D2, const float* __restrict__ c2,
    const float* __restrict__ D3, const float* __restrict__ c3,
    float* __restrict__ out)
{
    __shared__ float red8[8][HD];
    __shared__ float red2[2][HD];
    __shared__ float hb[HD];
    __shared__ float tb[HD];
    const int b = blockIdx.x;
    const int t = threadIdx.x;
    const int ch = t & 127, sl = t >> 7;

    {
        const float* base = partial + b * BPB * HD + ch;
        float s0 = 0.f, s1 = 0.f, s2 = 0.f, s3 = 0.f;
        int tl = sl;
        for (; tl + 32 <= BPB; tl += 32) {
            s0 += base[(tl     ) * HD];
            s1 += base[(tl +  8) * HD];
            s2 += base[(tl + 16) * HD];
            s3 += base[(tl + 24) * HD];
        }
        for (; tl < BPB; tl += 8) s0 += base[tl * HD];
        red8[sl][ch] = (s0 + s1) + (s2 + s3);
    }
    __syncthreads();
    if (sl == 0) {
        float v = ((red8[0][ch] + red8[1][ch]) + (red8[2][ch] + red8[3][ch]))
                + ((red8[4][ch] + red8[5][ch]) + (red8[6][ch] + red8[7][ch]));
        hb[ch] = fmaxf(v * (1.0f / 65536.0f), 0.0f);
    }
    __syncthreads();

    const int hf = sl & 1;

    if (t < 256) {
        float a = 0.f;
        for (int k = hf * 64; k < hf * 64 + 64; ++k)
            a = fmaf(hb[k], D1[(k << 7) + ch], a);
        red2[hf][ch] = a;
    }
    __syncthreads();
    if (t < 128)
        tb[ch] = fmaxf(red2[0][ch] + red2[1][ch] + c1[ch], 0.0f);
    __syncthreads();

    if (t < 256) {
        float a = 0.f;
        for (int k = hf * 64; k < hf * 64 + 64; ++k)
            a = fmaf(tb[k], D2[(k << 7) + ch], a);
        red2[hf][ch] = a;
    }
    __syncthreads();
    if (t < 128)
        hb[ch] = fmaxf(red2[0][ch] + red2[1][ch] + c2[ch], 0.0f);
    __syncthreads();

    if (t < 128) red2[0][ch] = hb[ch] * D3[ch];
    __syncthreads();
    if (t < 64) {
        float r = red2[0][t] + red2[0][t + 64];
#pragma unroll
        for (int s2 = 1; s2 < 64; s2 <<= 1)
            r += __shfl_xor(r, s2, 64);
        if (t == 0) out[b] = r + c3[0];
    }
}

extern "C" void kernel_launch(void* const* d_in, const int* in_sizes, int n_in,
                              void* d_out, int out_size, void* d_ws, size_t ws_size,
                              hipStream_t stream)
{
    (void)in_sizes; (void)n_in; (void)out_size; (void)ws_size;

    const int*   xcat  = (const int*)  d_in[0];
    const float* xfeat = (const float*)d_in[1];
    const float* emb   = (const float*)d_in[2];
    const float* W1    = (const float*)d_in[3];
    const float* b1    = (const float*)d_in[4];
    const float* W2    = (const float*)d_in[5];
    const float* b2    = (const float*)d_in[6];
    const float* W3    = (const float*)d_in[7];
    const float* b3    = (const float*)d_in[8];
    const float* D1    = (const float*)d_in[9];
    const float* c1    = (const float*)d_in[10];
    const float* D2    = (const float*)d_in[11];
    const float* c2    = (const float*)d_in[12];
    const float* D3    = (const float*)d_in[13];
    const float* c3    = (const float*)d_in[14];
    float* out = (float*)d_out;

    float* x       = (float*)d_ws;                    // 65536 f
    short* pw1     = (short*)(x + NB * NN * 64);      // 8192 s  (16 KB)
    short* pw2     = pw1 + 8 * 2 * 64 * 8;            // 16384 s (32 KB)
    short* pw3     = pw2 + 8 * 4 * 64 * 8;            // 16384 s (32 KB)
    float* partial = (float*)(pw3 + 8 * 4 * 64 * 8);  // 4*129*128 f

    prep_kernel<<<276, 256, 0, stream>>>(xcat, xfeat, emb, W1, W2, W3,
                                         x, pw1, pw2, pw3);
    pair_mlp<<<dim3(BPB, NB), 512, 0, stream>>>(x, pw1, b1, pw2, b2, pw3, b3, partial);
    reduce_decode<<<NB, 1024, 0, stream>>>(partial, D1, c1, D2, c2, D3, c3, out);
}